// Round 14
// baseline (5822.041 us; speedup 1.0000x reference)
//
#include <hip/hip_runtime.h>
#include <hip/hip_bf16.h>

#define H_DIM 1024
#define B_DIM 64
#define T_DIM 512
#define I_PAD 128
#define I_ORIG 118
#define FC_DIM 16
#define HB (B_DIM * H_DIM)

typedef __hip_bfloat16 bf16;
typedef __attribute__((ext_vector_type(8))) short short8v;
typedef __attribute__((ext_vector_type(4))) float f32x4;

#define MFMA16(a, b, c) __builtin_amdgcn_mfma_f32_16x16x32_bf16(a, b, c, 0, 0, 0)

__device__ __forceinline__ short8v ldg8(const bf16* p) {
    return *reinterpret_cast<const short8v*>(p);
}
// 16B load bypassing L1/L2 (fresh from coherence point)
__device__ __forceinline__ short8v ld_byp16(const bf16* p) {
    union { unsigned long long u[2]; short8v v; } r;
    const unsigned long long* q = reinterpret_cast<const unsigned long long*>(p);
    r.u[0] = __hip_atomic_load(q,     __ATOMIC_RELAXED, __HIP_MEMORY_SCOPE_AGENT);
    r.u[1] = __hip_atomic_load(q + 1, __ATOMIC_RELAXED, __HIP_MEMORY_SCOPE_AGENT);
    return r.v;
}
__device__ __forceinline__ unsigned short f2bf_bits(float f) {
    union { bf16 h; unsigned short s; } u;
    u.h = __float2bfloat16(f);
    return u.s;
}
__device__ __forceinline__ unsigned ld_coh(const unsigned* p) {
    return __hip_atomic_load(p, __ATOMIC_RELAXED, __HIP_MEMORY_SCOPE_AGENT);
}
__device__ __forceinline__ void st_coh(unsigned* p, unsigned v) {
    __hip_atomic_store(p, v, __ATOMIC_RELAXED, __HIP_MEMORY_SCOPE_AGENT);
}

// ---------------------------------------------------------------------------
// x[b][t][i] f32 -> x_bf[t][b][c] bf16 (c padded 118->128 with zeros)
// ---------------------------------------------------------------------------
__global__ __launch_bounds__(256) void cvt_x_kernel(
    const float* __restrict__ x, bf16* __restrict__ out)
{
    int idx  = blockIdx.x * 256 + threadIdx.x;
    int c    = idx & 127;
    int rest = idx >> 7;
    int b    = rest & 63;
    int t    = rest >> 6;
    float v  = (c < I_ORIG) ? x[((long)b * T_DIM + t) * I_ORIG + c] : 0.0f;
    out[idx] = __float2bfloat16(v);
}

__global__ __launch_bounds__(256) void cvt_pad(
    const float* __restrict__ in, bf16* __restrict__ out,
    int kin, int kp, long total)
{
    long idx = (long)blockIdx.x * 256 + threadIdx.x;
    if (idx >= total) return;
    int  c = (int)(idx % kp);
    long r = idx / kp;
    out[idx] = __float2bfloat16(c < kin ? in[r * kin + c] : 0.0f);
}

// ---------------------------------------------------------------------------
// Concurrent two-layer encoder, 1 BLOCK/CU for both layers.
// grid 256 x 256 (4 waves). bid<128: layer1; bid>=128: layer2.
// Block (lyr, grp in {0,1}, bn in [0,64)) owns output tile 32 batch rows x
// 16 j-cols. Waves = k-quarters. Whh (and L1's Wx1) fragments REGISTER-
// resident (96+ VGPR; 1 wave/SIMD so <=512 OK). LDS = reduce only (72KB dbuf).
// Per-step protocol = R7 verbatim; m=32 only adds parallel-issued work.
// Layer2: gi2 (input side) computed one step ahead post-flag (R13),
// in-step chain identical to L1's. Flags per layer: [grp][bn][w] = 512
// dwords; consumer lane polls 4 consecutive dwords (block bn=lane's 4 waves).
// ---------------------------------------------------------------------------
__global__ __launch_bounds__(256, 1) void gru_enc2(
    const bf16* __restrict__ x_bf,
    const bf16* __restrict__ Wx1, const bf16* __restrict__ Wh1,
    const bf16* __restrict__ Wx2, const bf16* __restrict__ Wh2,
    const float* __restrict__ bih1, const float* __restrict__ bhh1,
    const float* __restrict__ bih2, const float* __restrict__ bhh2,
    bf16* h1all,                    // slot s = h1(s-1); read t, write t+1
    bf16* h2rg,                     // ring: step t reads (t+3)&3, writes t&3
    float* hf1f, float* hf2f,
    unsigned* fl)
{
    extern __shared__ float sm_red[];     // 2 x 9216 floats (73728 B)

    const int tid  = threadIdx.x;
    const int w    = tid >> 6;
    const int lane = tid & 63;
    const int ln   = lane & 15;
    const int lk   = lane >> 4;
    const int bid  = blockIdx.x;
    const int lyr  = bid >> 7;
    const int b2   = bid & 127;
    const int bn   = b2 & 63;
    const int grp  = b2 >> 6;            // {0,1}: batch rows 32*grp..+32
    const int j0   = bn << 4;
    const int m0   = grp << 5;
    const int j    = j0 + ln;

    const int wko  = w << 8;             // hidden k-quarter base
    const int r0   = (w << 2) | lk;      // output row within m-half [0,16)
    const long opos0 = (long)(m0 + r0) * H_DIM + j;
    const long opos1 = opos0 + 16L * H_DIM;

    // ---- hidden-side weight fragments -> registers (once)
    const bf16* WhG = lyr ? Wh2 : Wh1;
    short8v whr[8], whz[8], whn[8];
    {
        const bf16* bp = WhG + (long)j * 1024 + wko + lk * 8;
#pragma unroll
        for (int ks = 0; ks < 8; ++ks) {
            whr[ks] = ldg8(bp + ks * 32);
            whz[ks] = ldg8(bp + (1 << 20) + ks * 32);
            whn[ks] = ldg8(bp + (2 << 20) + ks * 32);
        }
    }
    short8v wx_r{}, wx_z{}, wx_n{};
    if (lyr == 0) {
        const bf16* bx = Wx1 + (long)j * I_PAD + (w << 5) + lk * 8;
        wx_r = ldg8(bx);
        wx_z = ldg8(bx + (1 << 17));
        wx_n = ldg8(bx + (2 << 17));
    }

    const float* bihv = lyr ? bih2 : bih1;
    const float* bhhv = lyr ? bhh2 : bhh1;
    const float b_r  = bihv[j] + bhhv[j];
    const float b_z  = bihv[j + 1024] + bhhv[j + 1024];
    const float b_ni = bihv[j + 2048];
    const float b_nh = bhhv[j + 2048];

    unsigned* flbase = fl + (lyr << 9);
    unsigned* myflag = flbase + (grp << 8) + (bn << 2) + w;
    const unsigned* pollp  = flbase + (grp << 8) + (lane << 2);
    const unsigned* pollp1 = fl + (grp << 8) + (lane << 2);   // L1 flags

    float hprev0 = 0.0f, hprev1 = 0.0f;

#define POLL4(PTR, TGT)                                                      \
    {                                                                        \
        const unsigned _t = (TGT);                                           \
        while (true) {                                                       \
            unsigned f0 = ld_coh((PTR) + 0), f1 = ld_coh((PTR) + 1);         \
            unsigned f2 = ld_coh((PTR) + 2), f3 = ld_coh((PTR) + 3);         \
            int ok = (f0 >= _t) & (f1 >= _t) & (f2 >= _t) & (f3 >= _t);      \
            if (__all(ok)) break;                                            \
        }                                                                    \
        asm volatile("" ::: "memory");                                       \
    }

#define REDUCE_COMBINE(RED, A_R0, A_Z0, A_NI0, A_NH0, A_R1, A_Z1, A_NI1, A_NH1) \
    {                                                                        \
        _Pragma("unroll")                                                    \
        for (int a = 0; a < 4; ++a) {                                        \
            f32x4 v0 = (a == 0) ? A_R0 : (a == 1) ? A_Z0 : (a == 2) ? A_NI0 : A_NH0; \
            f32x4 v1 = (a == 0) ? A_R1 : (a == 1) ? A_Z1 : (a == 2) ? A_NI1 : A_NH1; \
            int base = ((w << 2) + a) * 576 + (lk << 2) * 18 + ln;           \
            _Pragma("unroll")                                                \
            for (int e = 0; e < 4; ++e) {                                    \
                (RED)[base + e * 18] = v0[e];                                \
                (RED)[base + 288 + e * 18] = v1[e];                          \
            }                                                                \
        }                                                                    \
        __syncthreads();                                                     \
        _Pragma("unroll")                                                    \
        for (int mh = 0; mh < 2; ++mh) {                                     \
            float sR = 0, sZ = 0, sNI = 0, sNH = 0;                          \
            _Pragma("unroll")                                                \
            for (int w2 = 0; w2 < 4; ++w2) {                                 \
                int tb = (w2 << 2) * 576 + mh * 288 + r0 * 18 + ln;          \
                sR  += (RED)[tb];                                            \
                sZ  += (RED)[tb + 576];                                      \
                sNI += (RED)[tb + 1152];                                     \
                sNH += (RED)[tb + 1728];                                     \
            }                                                                \
            float rr = 1.0f / (1.0f + __expf(-(sR + b_r)));                  \
            float zz = 1.0f / (1.0f + __expf(-(sZ + b_z)));                  \
            float xn = (sNI + b_ni) + rr * (sNH + b_nh);                     \
            float nn = 2.0f / (1.0f + __expf(-2.0f * xn)) - 1.0f;            \
            float hp = mh ? hprev1 : hprev0;                                 \
            float hv = (1.0f - zz) * nn + zz * hp;                           \
            if (mh) { hprev1 = hv; hv1 = hv; } else { hprev0 = hv; hv0 = hv; } \
        }                                                                    \
    }

    if (lyr == 0) {
        // =========================== LAYER 1 ===========================
        short8v xc0, xc1;
        {
            const bf16* xr = x_bf + (long)(m0 + ln) * I_PAD + (w << 5) + lk * 8;
            xc0 = ldg8(xr);
            xc1 = ldg8(xr + 16L * I_PAD);
        }
        for (int t = 0; t < T_DIM; ++t) {
            f32x4 aR0{0,0,0,0}, aZ0{0,0,0,0}, aNI0{0,0,0,0}, aNH0{0,0,0,0};
            f32x4 aR1{0,0,0,0}, aZ1{0,0,0,0}, aNI1{0,0,0,0}, aNH1{0,0,0,0};

            // x-side gates (pre-poll; register weights)
            aR0  = MFMA16(xc0, wx_r, aR0);  aR1  = MFMA16(xc1, wx_r, aR1);
            aZ0  = MFMA16(xc0, wx_z, aZ0);  aZ1  = MFMA16(xc1, wx_z, aZ1);
            aNI0 = MFMA16(xc0, wx_n, aNI0); aNI1 = MFMA16(xc1, wx_n, aNI1);

            if (t > 0) POLL4(pollp, (unsigned)t);

            // hidden A (cached; write-once slot t), both m-halves
            const bf16* ha0 = h1all + (long)t * HB + (long)(m0 + ln) * H_DIM
                              + wko + lk * 8;
            const bf16* ha1 = ha0 + 16L * H_DIM;
            short8v ah0[8], ah1[8];
#pragma unroll
            for (int ks = 0; ks < 8; ++ks) ah0[ks] = ldg8(ha0 + ks * 32);
#pragma unroll
            for (int ks = 0; ks < 8; ++ks) ah1[ks] = ldg8(ha1 + ks * 32);
#pragma unroll
            for (int ks = 0; ks < 8; ++ks) {
                aR0  = MFMA16(ah0[ks], whr[ks], aR0);
                aZ0  = MFMA16(ah0[ks], whz[ks], aZ0);
                aNH0 = MFMA16(ah0[ks], whn[ks], aNH0);
                aR1  = MFMA16(ah1[ks], whr[ks], aR1);
                aZ1  = MFMA16(ah1[ks], whz[ks], aZ1);
                aNH1 = MFMA16(ah1[ks], whn[ks], aNH1);
            }

            float hv0, hv1;
            float* red = sm_red + (t & 1) * 9216;
            REDUCE_COMBINE(red, aR0, aZ0, aNI0, aNH0, aR1, aZ1, aNI1, aNH1);

            bf16* dst = h1all + (long)(t + 1) * HB;
            float ho0 = __shfl_xor(hv0, 1), ho1 = __shfl_xor(hv1, 1);
            if ((ln & 1) == 0) {
                unsigned p0 = (unsigned)f2bf_bits(hv0) | ((unsigned)f2bf_bits(ho0) << 16);
                unsigned p1 = (unsigned)f2bf_bits(hv1) | ((unsigned)f2bf_bits(ho1) << 16);
                st_coh((unsigned*)(dst + (opos0 & ~1L)), p0);
                st_coh((unsigned*)(dst + (opos1 & ~1L)), p1);
            }
            if (t == T_DIM - 1) { hf1f[opos0] = hv0; hf1f[opos1] = hv1; }

            asm volatile("s_waitcnt vmcnt(0)" ::: "memory");
            if (lane == 0) st_coh(myflag, (unsigned)(t + 1));   // L2 needs 512
            if (t + 1 < T_DIM) {
                const bf16* xr = x_bf + (long)(t + 1) * (B_DIM * I_PAD)
                               + (long)(m0 + ln) * I_PAD + (w << 5) + lk * 8;
                xc0 = ldg8(xr);
                xc1 = ldg8(xr + 16L * I_PAD);
            }
        }
    } else {
        // =========================== LAYER 2 ===========================
        const bf16* wx2r = Wx2 + (long)j * 1024 + wko + lk * 8;

        f32x4 gR0{0,0,0,0}, gZ0{0,0,0,0}, gN0{0,0,0,0};
        f32x4 gR1{0,0,0,0}, gZ1{0,0,0,0}, gN1{0,0,0,0};
        // gi2(0): wait h1(0) (L1 flag >= 1), then accumulate
        {
            POLL4(pollp1, 1u);
            const bf16* xa0 = h1all + 1L * HB + (long)(m0 + ln) * H_DIM
                              + wko + lk * 8;
            const bf16* xa1 = xa0 + 16L * H_DIM;
#pragma unroll
            for (int ks = 0; ks < 8; ++ks) {
                short8v br  = ldg8(wx2r + ks * 32);
                short8v bz  = ldg8(wx2r + (1 << 20) + ks * 32);
                short8v bnn = ldg8(wx2r + (2 << 20) + ks * 32);
                short8v a0  = ldg8(xa0 + ks * 32);
                short8v a1  = ldg8(xa1 + ks * 32);
                gR0 = MFMA16(a0, br, gR0);   gR1 = MFMA16(a1, br, gR1);
                gZ0 = MFMA16(a0, bz, gZ0);   gZ1 = MFMA16(a1, bz, gZ1);
                gN0 = MFMA16(a0, bnn, gN0);  gN1 = MFMA16(a1, bnn, gN1);
            }
        }

        for (int t = 0; t < T_DIM; ++t) {
            if (t > 0) POLL4(pollp, (unsigned)t);

            f32x4 aR0 = gR0, aZ0 = gZ0, aNI0 = gN0, aNH0{0,0,0,0};
            f32x4 aR1 = gR1, aZ1 = gZ1, aNI1 = gN1, aNH1{0,0,0,0};

            // hidden A (bypass; ring slot (t+3)&3), both m-halves
            const bf16* hb0 = h2rg + (long)((t + 3) & 3) * HB
                              + (long)(m0 + ln) * H_DIM + wko + lk * 8;
            const bf16* hb1 = hb0 + 16L * H_DIM;
            short8v ah0[8], ah1[8];
#pragma unroll
            for (int ks = 0; ks < 8; ++ks) ah0[ks] = ld_byp16(hb0 + ks * 32);
#pragma unroll
            for (int ks = 0; ks < 8; ++ks) ah1[ks] = ld_byp16(hb1 + ks * 32);
#pragma unroll
            for (int ks = 0; ks < 8; ++ks) {
                aR0  = MFMA16(ah0[ks], whr[ks], aR0);
                aZ0  = MFMA16(ah0[ks], whz[ks], aZ0);
                aNH0 = MFMA16(ah0[ks], whn[ks], aNH0);
                aR1  = MFMA16(ah1[ks], whr[ks], aR1);
                aZ1  = MFMA16(ah1[ks], whz[ks], aZ1);
                aNH1 = MFMA16(ah1[ks], whn[ks], aNH1);
            }

            float hv0, hv1;
            float* red = sm_red + (t & 1) * 9216;
            REDUCE_COMBINE(red, aR0, aZ0, aNI0, aNH0, aR1, aZ1, aNI1, aNH1);

            bf16* dst = h2rg + (long)(t & 3) * HB;
            float ho0 = __shfl_xor(hv0, 1), ho1 = __shfl_xor(hv1, 1);
            if ((ln & 1) == 0) {
                unsigned p0 = (unsigned)f2bf_bits(hv0) | ((unsigned)f2bf_bits(ho0) << 16);
                unsigned p1 = (unsigned)f2bf_bits(hv1) | ((unsigned)f2bf_bits(ho1) << 16);
                st_coh((unsigned*)(dst + (opos0 & ~1L)), p0);
                st_coh((unsigned*)(dst + (opos1 & ~1L)), p1);
            }
            if (t == T_DIM - 1) { hf2f[opos0] = hv0; hf2f[opos1] = hv1; }

            asm volatile("s_waitcnt vmcnt(0)" ::: "memory");
            if (lane == 0 && t + 1 < T_DIM) st_coh(myflag, (unsigned)(t + 1));

            // gi2(t+1) in the post-flag shadow
            if (t + 1 < T_DIM) {
                POLL4(pollp1, (unsigned)(t + 2));
                const bf16* xa0 = h1all + (long)(t + 2) * HB
                                  + (long)(m0 + ln) * H_DIM + wko + lk * 8;
                const bf16* xa1 = xa0 + 16L * H_DIM;
                gR0 = f32x4{0,0,0,0}; gZ0 = f32x4{0,0,0,0}; gN0 = f32x4{0,0,0,0};
                gR1 = f32x4{0,0,0,0}; gZ1 = f32x4{0,0,0,0}; gN1 = f32x4{0,0,0,0};
#pragma unroll
                for (int ks = 0; ks < 8; ++ks) {
                    short8v br  = ldg8(wx2r + ks * 32);
                    short8v bz  = ldg8(wx2r + (1 << 20) + ks * 32);
                    short8v bnn = ldg8(wx2r + (2 << 20) + ks * 32);
                    short8v a0  = ldg8(xa0 + ks * 32);
                    short8v a1  = ldg8(xa1 + ks * 32);
                    gR0 = MFMA16(a0, br, gR0);   gR1 = MFMA16(a1, br, gR1);
                    gZ0 = MFMA16(a0, bz, gZ0);   gZ1 = MFMA16(a1, bz, gZ1);
                    gN0 = MFMA16(a0, bnn, gN0);  gN1 = MFMA16(a1, bnn, gN1);
                }
            }
        }
    }
#undef POLL4
#undef REDUCE_COMBINE
}

// ---------------------------------------------------------------------------
// Single-step GRU cell (decoder) — R7 kernel.
// ---------------------------------------------------------------------------
template<int WXK, bool WXG, bool SEQ>
__global__ __launch_bounds__(256, 1) void gru_pass(
    const bf16* __restrict__ xbase, long xstride,
    const bf16* __restrict__ WxG,
    const bf16* __restrict__ WhG,
    const float* __restrict__ bih, const float* __restrict__ bhh,
    const bf16* hin, bf16* hout,
    const float* f_init, float* f_final,
    int nsteps, unsigned* flags)
{
    extern __shared__ char smem[];
    constexpr int WH_BYTES = 3 * 16 * 1024 * 2;
    constexpr int WX_BYTES = WXG ? 0 : 3 * 16 * WXK * 2;
    float* sm_red = (float*)(smem + WH_BYTES + WX_BYTES);

    const int tid  = threadIdx.x;
    const int w    = tid >> 6;
    const int lane = tid & 63;
    const int ln   = lane & 15;
    const int lk   = lane >> 4;
    const int bid  = blockIdx.x;
    const int bn   = bid & 63;
    const int grp  = bid >> 6;
    const int j0   = bn * 16;
    const int m0   = grp * 16;
    const int j    = j0 + ln;

    for (int c = tid; c < WH_BYTES / 16; c += 256) {
        int lin = c * 16;
        int row = lin >> 11;
        int wb  = lin & 2047;
        int g   = row >> 4, jj = row & 15;
        const bf16* src = WhG + ((long)(g * 1024 + j0 + jj) << 10) + (wb >> 1);
        *reinterpret_cast<short8v*>(smem + (lin ^ ((jj & 7) << 4))) = ldg8(src);
    }
    if constexpr (!WXG) {
        for (int c = tid; c < WX_BYTES / 16; c += 256) {
            int lin = c * 16;
            int row = lin / (WXK * 2);
            int wb  = lin % (WXK * 2);
            int g   = row >> 4, jj = row & 15;
            const bf16* src = WxG + (long)(g * 1024 + j0 + jj) * WXK + (wb >> 1);
            *reinterpret_cast<short8v*>(smem + WH_BYTES + (lin ^ ((jj & 7) << 4))) = ldg8(src);
        }
    }
    __syncthreads();

    const int wkoh = w << 8;
    const int wkox = (WXK == 128) ? (w << 5) : (w << 8);
    const int swz  = (ln & 7) << 4;
    const int whb0 = ln * 2048 + ((wkoh + lk * 8) << 1);

    const float bias_r  = bih[j] + bhh[j];
    const float bias_z  = bih[j + H_DIM] + bhh[j + H_DIM];
    const float bias_ni = bih[j + 2 * H_DIM];
    const float bias_nh = bhh[j + 2 * H_DIM];

    const int  crow = (w << 2) | lk;
    const int  gm   = m0 + crow;
    const long opos = (long)gm * H_DIM + j;

    float hprev = f_init ? f_init[opos] : 0.0f;

    constexpr int NKX = (WXK == 128) ? 1 : 8;
    short8v xcur[NKX];
    {
        const bf16* xr = xbase + (long)(m0 + ln) * WXK + wkox + lk * 8;
#pragma unroll
        for (int ks = 0; ks < NKX; ++ks) xcur[ks] = ldg8(xr + ks * 32);
    }

    for (int t = 0; t < nsteps; ++t) {
        f32x4 aR{0,0,0,0}, aZ{0,0,0,0}, aNI{0,0,0,0}, aNH{0,0,0,0};

        if constexpr (WXK == 128) {
            int o = WH_BYTES + ln * 256 + ((wkox + lk * 8) << 1);
            short8v br  = *(const short8v*)(smem + ((o       ) ^ swz));
            short8v bz  = *(const short8v*)(smem + ((o + 4096) ^ swz));
            short8v bnn = *(const short8v*)(smem + ((o + 8192) ^ swz));
            aR  = MFMA16(xcur[0], br,  aR);
            aZ  = MFMA16(xcur[0], bz,  aZ);
            aNI = MFMA16(xcur[0], bnn, aNI);
        } else {
            const bf16* wxr = WxG + (long)(j0 + ln) * 1024 + wkox + lk * 8;
#pragma unroll
            for (int ks = 0; ks < 8; ++ks) {
                short8v br  = ldg8(wxr + ks * 32);
                short8v bz  = ldg8(wxr + (1 << 20) + ks * 32);
                short8v bnn = ldg8(wxr + (2 << 20) + ks * 32);
                aR  = MFMA16(xcur[ks], br,  aR);
                aZ  = MFMA16(xcur[ks], bz,  aZ);
                aNI = MFMA16(xcur[ks], bnn, aNI);
            }
        }

        const bf16* bf_in = SEQ ? hin + (long)t * HB : hin + (long)(t & 1) * HB;
        const bf16* ha = bf_in + (long)(m0 + ln) * H_DIM + wkoh + lk * 8;
        short8v ah[8];
#pragma unroll
        for (int ks = 0; ks < 8; ++ks)
            ah[ks] = SEQ ? ldg8(ha + ks * 32) : ld_byp16(ha + ks * 32);

#pragma unroll
        for (int ks = 0; ks < 8; ++ks) {
            int o = whb0 + ks * 64;
            short8v br  = *(const short8v*)(smem + ((o        ) ^ swz));
            short8v bz  = *(const short8v*)(smem + ((o + 32768) ^ swz));
            short8v bnn = *(const short8v*)(smem + ((o + 65536) ^ swz));
            aR  = MFMA16(ah[ks], br,  aR);
            aZ  = MFMA16(ah[ks], bz,  aZ);
            aNH = MFMA16(ah[ks], bnn, aNH);
        }

        float* red = sm_red + (t & 1) * 4608;
#pragma unroll
        for (int a = 0; a < 4; ++a) {
            f32x4 v = (a == 0) ? aR : (a == 1) ? aZ : (a == 2) ? aNI : aNH;
            int base = ((w << 2) + a) * 288 + (lk * 4) * 18 + ln;
#pragma unroll
            for (int e = 0; e < 4; ++e)
                red[base + e * 18] = v[e];
        }
        __syncthreads();

        float sR = 0, sZ = 0, sNI = 0, sNH = 0;
#pragma unroll
        for (int w2 = 0; w2 < 4; ++w2) {
            int tb = (w2 << 2) * 288 + crow * 18 + ln;
            sR  += red[tb];
            sZ  += red[tb + 288];
            sNI += red[tb + 576];
            sNH += red[tb + 864];
        }
        float rr = 1.0f / (1.0f + __expf(-(sR + bias_r)));
        float zz = 1.0f / (1.0f + __expf(-(sZ + bias_z)));
        float xn = (sNI + bias_ni) + rr * (sNH + bias_nh);
        float nn = 2.0f / (1.0f + __expf(-2.0f * xn)) - 1.0f;
        float hv = (1.0f - zz) * nn + zz * hprev;
        hprev = hv;

        {
            bf16* wr = SEQ ? hout + (long)t * HB
                           : const_cast<bf16*>(hin) + (long)((t + 1) & 1) * HB;
            float ho = __shfl_xor(hv, 1);
            if ((ln & 1) == 0) {
                unsigned pk = (unsigned)f2bf_bits(hv)
                            | ((unsigned)f2bf_bits(ho) << 16);
                st_coh((unsigned*)(wr + (opos & ~1L)), pk);
            }
        }
        if (t == nsteps - 1 && f_final) f_final[opos] = hv;
        (void)flags;
    }
}

// ---------------------------------------------------------------------------
__global__ __launch_bounds__(1024) void head_kernel(
    const float* __restrict__ h2,
    const float* __restrict__ fc_W, const float* __restrict__ fc_b,
    const float* __restrict__ out_W, const float* __restrict__ out_b,
    float* __restrict__ y)
{
    __shared__ float acc_s[FC_DIM][B_DIM];
    const int b = threadIdx.x & 63;
    const int f = threadIdx.x >> 6;
    const float* wp = fc_W + (long)f * H_DIM;
    const float* hp = h2 + (long)b * H_DIM;
    float a = fc_b[f];
#pragma unroll 8
    for (int k = 0; k < H_DIM; ++k)
        a = fmaf(hp[k], wp[k], a);
    a = fmaxf(a, 0.0f);
    acc_s[f][b] = a * out_W[f];
    __syncthreads();
    if (threadIdx.x < 64) {
        float s = out_b[0];
#pragma unroll
        for (int f2 = 0; f2 < FC_DIM; ++f2) s += acc_s[f2][b];
        y[b] = s;
    }
}

// ---------------------------------------------------------------------------
extern "C" void kernel_launch(void* const* d_in, const int* in_sizes, int n_in,
                              void* d_out, int out_size, void* d_ws, size_t ws_size,
                              hipStream_t stream)
{
    const float* x      = (const float*)d_in[0];
    const float* e_Wih0 = (const float*)d_in[1];
    const float* e_Whh0 = (const float*)d_in[2];
    const float* e_bih0 = (const float*)d_in[3];
    const float* e_bhh0 = (const float*)d_in[4];
    const float* e_Wih1 = (const float*)d_in[5];
    const float* e_Whh1 = (const float*)d_in[6];
    const float* e_bih1 = (const float*)d_in[7];
    const float* e_bhh1 = (const float*)d_in[8];
    const float* d_Wih0 = (const float*)d_in[9];
    const float* d_Whh0 = (const float*)d_in[10];
    const float* d_bih0 = (const float*)d_in[11];
    const float* d_bhh0 = (const float*)d_in[12];
    const float* d_Wih1 = (const float*)d_in[13];
    const float* d_Whh1 = (const float*)d_in[14];
    const float* d_bih1 = (const float*)d_in[15];
    const float* d_bhh1 = (const float*)d_in[16];
    const float* fc_W   = (const float*)d_in[17];
    const float* fc_b   = (const float*)d_in[18];
    const float* out_W  = (const float*)d_in[19];
    const float* out_b  = (const float*)d_in[20];
    (void)in_sizes; (void)n_in; (void)out_size; (void)ws_size;

    char* p = (char*)d_ws;
    auto alloc = [&](size_t bytes) -> char* {
        char* r = p; p += (bytes + 255) & ~(size_t)255; return r;
    };
    bf16*  x_bf  = (bf16*)alloc((size_t)T_DIM * B_DIM * I_PAD * 2);
    bf16*  wih0e = (bf16*)alloc(3072ull * 128 * 2);
    bf16*  whh0e = (bf16*)alloc(3072ull * 1024 * 2);
    bf16*  wih1e = (bf16*)alloc(3072ull * 1024 * 2);
    bf16*  whh1e = (bf16*)alloc(3072ull * 1024 * 2);
    bf16*  wih0d = (bf16*)alloc(3072ull * 128 * 2);
    bf16*  whh0d = (bf16*)alloc(3072ull * 1024 * 2);
    bf16*  wih1d = (bf16*)alloc(3072ull * 1024 * 2);
    bf16*  whh1d = (bf16*)alloc(3072ull * 1024 * 2);
    bf16*  h1all = (bf16*)alloc(514ull * HB * 2);   // slots 0..513
    bf16*  h2rg  = (bf16*)alloc(5ull * HB * 2);     // 4-slot ring + spare
    bf16*  hd1b  = (bf16*)alloc((size_t)HB * 2);
    float* hf1f  = (float*)alloc((size_t)HB * 4);
    float* hf2f  = (float*)alloc((size_t)HB * 4);
    float* hd1f  = (float*)alloc((size_t)HB * 4);
    float* hd2f  = (float*)alloc((size_t)HB * 4);
    unsigned* fl = (unsigned*)alloc(8192);          // 2 layers x 512 dwords

    constexpr int RED = 2 * 4608 * 4;
    constexpr int SE  = 2 * 9216 * 4;               // enc2: 73728
    constexpr int S1  = 98304 + 12288 + RED;        // decoder cell 1
    constexpr int S2  = 98304 + RED;                // decoder cell 2
    (void)hipFuncSetAttribute((const void*)gru_enc2,
                              hipFuncAttributeMaxDynamicSharedMemorySize, SE);
    (void)hipFuncSetAttribute((const void*)gru_pass<128, false, true>,
                              hipFuncAttributeMaxDynamicSharedMemorySize, S1);
    (void)hipFuncSetAttribute((const void*)gru_pass<1024, true, false>,
                              hipFuncAttributeMaxDynamicSharedMemorySize, S2);

    cvt_x_kernel<<<(T_DIM * B_DIM * I_PAD) / 256, 256, 0, stream>>>(x, x_bf);
    auto cvt = [&](const float* in, bf16* out, int kin, int kp) {
        long total = 3072L * kp;
        cvt_pad<<<(int)((total + 255) / 256), 256, 0, stream>>>(in, out, kin, kp, total);
    };
    cvt(e_Wih0, wih0e, 118, 128);
    cvt(e_Whh0, whh0e, 1024, 1024);
    cvt(e_Wih1, wih1e, 1024, 1024);
    cvt(e_Whh1, whh1e, 1024, 1024);
    cvt(d_Wih0, wih0d, 118, 128);
    cvt(d_Whh0, whh0d, 1024, 1024);
    cvt(d_Wih1, wih1d, 1024, 1024);
    cvt(d_Whh1, whh1d, 1024, 1024);

    // deterministic per-launch state
    hipMemsetAsync(h1all, 0, (size_t)HB * 2, stream);            // h1(-1) = 0
    hipMemsetAsync(h2rg + 3ull * HB, 0, (size_t)HB * 2, stream); // h2(-1) = 0 (slot 3)
    hipMemsetAsync(fl,    0, 8192, stream);

    // concurrent two-layer encoder: 256 blocks (0-127 L1, 128-255 L2), 1/CU
    gru_enc2<<<256, 256, SE, stream>>>(
        x_bf, wih0e, whh0e, wih1e, whh1e,
        e_bih0, e_bhh0, e_bih1, e_bhh1,
        h1all, h2rg, hf1f, hf2f, fl);
    // h1(511) -> h1all slot 512 (+ hf1f); h2(511) -> ring slot 511&3 = 3 (+ hf2f)

    // decoder cell 1: x = x[:,511,:], h = h1(511) (cached write-once slot)
    gru_pass<128, false, true><<<256, 256, S1, stream>>>(
        x_bf + 511L * B_DIM * I_PAD, 0, wih0d, whh0d, d_bih0, d_bhh0,
        h1all + 512L * HB, hd1b, hf1f, hd1f, 1, nullptr);

    // decoder cell 2: x = hd1, h = h2(511) (ring slot 3; bypass reads;
    // dummy bf16 out lands in ring slot 4 = spare)
    gru_pass<1024, true, false><<<256, 256, S2, stream>>>(
        hd1b, 0, wih1d, whh1d, d_bih1, d_bhh1,
        h2rg + 3L * HB, nullptr, hf2f, hd2f, 1, nullptr);

    head_kernel<<<1, 1024, 0, stream>>>(hd2f, fc_W, fc_b, out_W, out_b,
                                        (float*)d_out);
}

// Round 15
// 4183.905 us; speedup vs baseline: 1.3915x; 1.3915x over previous
//
#include <hip/hip_runtime.h>
#include <hip/hip_bf16.h>

#define H_DIM 1024
#define B_DIM 64
#define T_DIM 512
#define I_PAD 128
#define I_ORIG 118
#define FC_DIM 16
#define HB (B_DIM * H_DIM)

typedef __hip_bfloat16 bf16;
typedef __attribute__((ext_vector_type(8))) short short8v;
typedef __attribute__((ext_vector_type(4))) float f32x4;

#define MFMA16(a, b, c) __builtin_amdgcn_mfma_f32_16x16x32_bf16(a, b, c, 0, 0, 0)

__device__ __forceinline__ short8v ldg8(const bf16* p) {
    return *reinterpret_cast<const short8v*>(p);
}
// 16B load bypassing L1/L2 (fresh from coherence point)
__device__ __forceinline__ short8v ld_byp16(const bf16* p) {
    union { unsigned long long u[2]; short8v v; } r;
    const unsigned long long* q = reinterpret_cast<const unsigned long long*>(p);
    r.u[0] = __hip_atomic_load(q,     __ATOMIC_RELAXED, __HIP_MEMORY_SCOPE_AGENT);
    r.u[1] = __hip_atomic_load(q + 1, __ATOMIC_RELAXED, __HIP_MEMORY_SCOPE_AGENT);
    return r.v;
}
__device__ __forceinline__ unsigned short f2bf_bits(float f) {
    union { bf16 h; unsigned short s; } u;
    u.h = __float2bfloat16(f);
    return u.s;
}
__device__ __forceinline__ unsigned ld_coh(const unsigned* p) {
    return __hip_atomic_load(p, __ATOMIC_RELAXED, __HIP_MEMORY_SCOPE_AGENT);
}
__device__ __forceinline__ void st_coh(unsigned* p, unsigned v) {
    __hip_atomic_store(p, v, __ATOMIC_RELAXED, __HIP_MEMORY_SCOPE_AGENT);
}

// ---------------------------------------------------------------------------
// x[b][t][i] f32 -> x_bf[t][b][c] bf16 (c padded 118->128 with zeros)
// ---------------------------------------------------------------------------
__global__ __launch_bounds__(256) void cvt_x_kernel(
    const float* __restrict__ x, bf16* __restrict__ out)
{
    int idx  = blockIdx.x * 256 + threadIdx.x;
    int c    = idx & 127;
    int rest = idx >> 7;
    int b    = rest & 63;
    int t    = rest >> 6;
    float v  = (c < I_ORIG) ? x[((long)b * T_DIM + t) * I_ORIG + c] : 0.0f;
    out[idx] = __float2bfloat16(v);
}

__global__ __launch_bounds__(256) void cvt_pad(
    const float* __restrict__ in, bf16* __restrict__ out,
    int kin, int kp, long total)
{
    long idx = (long)blockIdx.x * 256 + threadIdx.x;
    if (idx >= total) return;
    int  c = (int)(idx % kp);
    long r = idx / kp;
    out[idx] = __float2bfloat16(c < kin ? in[r * kin + c] : 0.0f);
}

// ---------------------------------------------------------------------------
// Persistent GRU pass, R7 protocol + REGISTER-RESIDENT hidden weights.
// grid 256 x 256 (4 waves). bn = bid&63 (j-tile 16), grp = bid>>6 (batch-16).
// Whh B-fragments (24 x 16B/lane = 96 VGPR) loaded once into registers;
// WXK==128: Wx fragments (3 x 16B) also registers. WXK==1024: Wx streamed
// from global pre-poll (XCD-L2 resident). LDS = reduce buffer only (36KB).
// Per-step: x-side MFMAs (pre-poll) -> bare-spin poll of 64 producer flags
// -> 8 A-fragment loads (cached if SEQ else sc1-bypass) -> 24 register MFMAs
// -> padded-LDS K-reduce (1 sync, dbuf) -> combine (register f32 hprev)
// -> pair-packed sc1 store -> vmcnt(0) -> per-wave flag -> x prefetch.
// ---------------------------------------------------------------------------
template<int WXK, bool SEQ>
__global__ __launch_bounds__(256, 1) void gru_pass(
    const bf16* __restrict__ xbase, long xstride,
    const bf16* __restrict__ Wx,    // [3*1024][WXK]
    const bf16* __restrict__ Wh,    // [3*1024][1024]
    const float* __restrict__ bih, const float* __restrict__ bhh,
    const bf16* hin,                // SEQ: slot array (read slot t); !SEQ: ping-pong
    bf16* hout,                     // SEQ: out base (write hout + t*HB); !SEQ: unused
    const float* f_init, float* f_final,
    int nsteps, unsigned* flags)
{
    __shared__ float sm_red[2 * 4608];

    const int tid  = threadIdx.x;
    const int w    = tid >> 6;
    const int lane = tid & 63;
    const int ln   = lane & 15;
    const int lk   = lane >> 4;
    const int bid  = blockIdx.x;
    const int bn   = bid & 63;
    const int grp  = bid >> 6;
    const int j0   = bn * 16;
    const int m0   = grp * 16;
    const int j    = j0 + ln;

    const int wkoh = w << 8;
    const int wkox = (WXK == 128) ? (w << 5) : (w << 8);
    const int crow = (w << 2) | lk;
    const int gm   = m0 + crow;
    const long opos = (long)gm * H_DIM + j;

    // ---- hidden-side weight fragments -> registers (once)
    short8v whr[8], whz[8], whn[8];
    {
        const bf16* bp = Wh + (long)j * 1024 + wkoh + lk * 8;
#pragma unroll
        for (int ks = 0; ks < 8; ++ks) {
            whr[ks] = ldg8(bp + ks * 32);
            whz[ks] = ldg8(bp + (1 << 20) + ks * 32);
            whn[ks] = ldg8(bp + (2 << 20) + ks * 32);
        }
    }
    // x-side fragments: registers if K=128, else streamed per step
    short8v wx_r{}, wx_z{}, wx_n{};
    if constexpr (WXK == 128) {
        const bf16* bx = Wx + (long)j * I_PAD + wkox + lk * 8;
        wx_r = ldg8(bx);
        wx_z = ldg8(bx + (1 << 17));
        wx_n = ldg8(bx + (2 << 17));
    }

    const float bias_r  = bih[j] + bhh[j];
    const float bias_z  = bih[j + H_DIM] + bhh[j + H_DIM];
    const float bias_ni = bih[j + 2 * H_DIM];
    const float bias_nh = bhh[j + 2 * H_DIM];

    float hprev = f_init ? f_init[opos] : 0.0f;

    unsigned* myflag = flags ? flags + (grp << 8) + (bn << 2) + w : nullptr;
    const unsigned* pollp = flags ? flags + (grp << 8) + (w << 6) + lane : nullptr;

    constexpr int NKX = (WXK == 128) ? 1 : 8;
    short8v xcur[NKX];
    {
        const bf16* xr = xbase + (long)(m0 + ln) * WXK + wkox + lk * 8;
#pragma unroll
        for (int ks = 0; ks < NKX; ++ks) xcur[ks] = ldg8(xr + ks * 32);
    }

    for (int t = 0; t < nsteps; ++t) {
        f32x4 aR{0,0,0,0}, aZ{0,0,0,0}, aNI{0,0,0,0}, aNH{0,0,0,0};

        // ---- input-side gates (pre-poll)
        if constexpr (WXK == 128) {
            aR  = MFMA16(xcur[0], wx_r, aR);
            aZ  = MFMA16(xcur[0], wx_z, aZ);
            aNI = MFMA16(xcur[0], wx_n, aNI);
        } else {
            const bf16* wxr = Wx + (long)j * 1024 + wkox + lk * 8;
#pragma unroll
            for (int ks = 0; ks < 8; ++ks) {
                short8v br  = ldg8(wxr + ks * 32);
                short8v bz  = ldg8(wxr + (1 << 20) + ks * 32);
                short8v bnn = ldg8(wxr + (2 << 20) + ks * 32);
                aR  = MFMA16(xcur[ks], br,  aR);
                aZ  = MFMA16(xcur[ks], bz,  aZ);
                aNI = MFMA16(xcur[ks], bnn, aNI);
            }
        }

        // ---- bare-spin on this wave's 64 producer flags
        if (flags && t > 0) {
            const unsigned tgt = (unsigned)t;
            while (true) {
                unsigned fv = ld_coh(pollp);
                if (__all((int)(fv >= tgt))) break;
            }
            asm volatile("" ::: "memory");
        }

        // ---- hidden A fragments + register-weight MFMAs
        const bf16* bf_in = SEQ ? hin + (long)t * HB : hin + (long)(t & 1) * HB;
        const bf16* ha = bf_in + (long)(m0 + ln) * H_DIM + wkoh + lk * 8;
        short8v ah[8];
#pragma unroll
        for (int ks = 0; ks < 8; ++ks)
            ah[ks] = SEQ ? ldg8(ha + ks * 32) : ld_byp16(ha + ks * 32);
#pragma unroll
        for (int ks = 0; ks < 8; ++ks) {
            aR  = MFMA16(ah[ks], whr[ks], aR);
            aZ  = MFMA16(ah[ks], whz[ks], aZ);
            aNH = MFMA16(ah[ks], whn[ks], aNH);
        }

        // ---- K-split reduce (18-word padded rows, dbuf, one sync)
        float* red = sm_red + (t & 1) * 4608;
#pragma unroll
        for (int a = 0; a < 4; ++a) {
            f32x4 v = (a == 0) ? aR : (a == 1) ? aZ : (a == 2) ? aNI : aNH;
            int base = ((w << 2) + a) * 288 + (lk * 4) * 18 + ln;
#pragma unroll
            for (int e = 0; e < 4; ++e)
                red[base + e * 18] = v[e];
        }
        __syncthreads();

        float sR = 0, sZ = 0, sNI = 0, sNH = 0;
#pragma unroll
        for (int w2 = 0; w2 < 4; ++w2) {
            int tb = (w2 << 2) * 288 + crow * 18 + ln;
            sR  += red[tb];
            sZ  += red[tb + 288];
            sNI += red[tb + 576];
            sNH += red[tb + 864];
        }
        float rr = 1.0f / (1.0f + __expf(-(sR + bias_r)));
        float zz = 1.0f / (1.0f + __expf(-(sZ + bias_z)));
        float xn = (sNI + bias_ni) + rr * (sNH + bias_nh);
        float nn = 2.0f / (1.0f + __expf(-2.0f * xn)) - 1.0f;
        float hv = (1.0f - zz) * nn + zz * hprev;
        hprev = hv;

        // ---- h store (pair-packed bf16, sc1)
        {
            bf16* wr = SEQ ? hout + (long)t * HB
                           : const_cast<bf16*>(hin) + (long)((t + 1) & 1) * HB;
            float ho = __shfl_xor(hv, 1);
            if ((ln & 1) == 0) {
                unsigned pk = (unsigned)f2bf_bits(hv)
                            | ((unsigned)f2bf_bits(ho) << 16);
                st_coh((unsigned*)(wr + (opos & ~1L)), pk);
            }
        }

        // ---- ack ONLY the store, then flag, then prefetch (off-chain)
        if (flags && t + 1 < nsteps) {
            asm volatile("s_waitcnt vmcnt(0)" ::: "memory");
            if (lane == 0) st_coh(myflag, (unsigned)(t + 1));
        }
        if (t + 1 < nsteps) {
            const bf16* xr = xbase + (long)(t + 1) * xstride
                             + (long)(m0 + ln) * WXK + wkox + lk * 8;
#pragma unroll
            for (int ks = 0; ks < NKX; ++ks) xcur[ks] = ldg8(xr + ks * 32);
        }

        if (t == nsteps - 1 && f_final) f_final[opos] = hv;
    }
}

// ---------------------------------------------------------------------------
__global__ __launch_bounds__(1024) void head_kernel(
    const float* __restrict__ h2,
    const float* __restrict__ fc_W, const float* __restrict__ fc_b,
    const float* __restrict__ out_W, const float* __restrict__ out_b,
    float* __restrict__ y)
{
    __shared__ float acc_s[FC_DIM][B_DIM];
    const int b = threadIdx.x & 63;
    const int f = threadIdx.x >> 6;
    const float* wp = fc_W + (long)f * H_DIM;
    const float* hp = h2 + (long)b * H_DIM;
    float a = fc_b[f];
#pragma unroll 8
    for (int k = 0; k < H_DIM; ++k)
        a = fmaf(hp[k], wp[k], a);
    a = fmaxf(a, 0.0f);
    acc_s[f][b] = a * out_W[f];
    __syncthreads();
    if (threadIdx.x < 64) {
        float s = out_b[0];
#pragma unroll
        for (int f2 = 0; f2 < FC_DIM; ++f2) s += acc_s[f2][b];
        y[b] = s;
    }
}

// ---------------------------------------------------------------------------
extern "C" void kernel_launch(void* const* d_in, const int* in_sizes, int n_in,
                              void* d_out, int out_size, void* d_ws, size_t ws_size,
                              hipStream_t stream)
{
    const float* x      = (const float*)d_in[0];
    const float* e_Wih0 = (const float*)d_in[1];
    const float* e_Whh0 = (const float*)d_in[2];
    const float* e_bih0 = (const float*)d_in[3];
    const float* e_bhh0 = (const float*)d_in[4];
    const float* e_Wih1 = (const float*)d_in[5];
    const float* e_Whh1 = (const float*)d_in[6];
    const float* e_bih1 = (const float*)d_in[7];
    const float* e_bhh1 = (const float*)d_in[8];
    const float* d_Wih0 = (const float*)d_in[9];
    const float* d_Whh0 = (const float*)d_in[10];
    const float* d_bih0 = (const float*)d_in[11];
    const float* d_bhh0 = (const float*)d_in[12];
    const float* d_Wih1 = (const float*)d_in[13];
    const float* d_Whh1 = (const float*)d_in[14];
    const float* d_bih1 = (const float*)d_in[15];
    const float* d_bhh1 = (const float*)d_in[16];
    const float* fc_W   = (const float*)d_in[17];
    const float* fc_b   = (const float*)d_in[18];
    const float* out_W  = (const float*)d_in[19];
    const float* out_b  = (const float*)d_in[20];
    (void)in_sizes; (void)n_in; (void)out_size; (void)ws_size;

    char* p = (char*)d_ws;
    auto alloc = [&](size_t bytes) -> char* {
        char* r = p; p += (bytes + 255) & ~(size_t)255; return r;
    };
    bf16*  x_bf  = (bf16*)alloc((size_t)T_DIM * B_DIM * I_PAD * 2);
    bf16*  wih0e = (bf16*)alloc(3072ull * 128 * 2);
    bf16*  whh0e = (bf16*)alloc(3072ull * 1024 * 2);
    bf16*  wih1e = (bf16*)alloc(3072ull * 1024 * 2);
    bf16*  whh1e = (bf16*)alloc(3072ull * 1024 * 2);
    bf16*  wih0d = (bf16*)alloc(3072ull * 128 * 2);
    bf16*  whh0d = (bf16*)alloc(3072ull * 1024 * 2);
    bf16*  wih1d = (bf16*)alloc(3072ull * 1024 * 2);
    bf16*  whh1d = (bf16*)alloc(3072ull * 1024 * 2);
    bf16*  h1all = (bf16*)alloc(513ull * HB * 2);   // slot s = h1 after s steps
    bf16*  h2pp  = (bf16*)alloc(2ull * HB * 2);     // pass-2 ping-pong
    bf16*  hd1b  = (bf16*)alloc((size_t)HB * 2);
    bf16*  hd2b  = (bf16*)alloc((size_t)HB * 2);
    float* hf1f  = (float*)alloc((size_t)HB * 4);   // pass-1 final f32 h
    float* hf2f  = (float*)alloc((size_t)HB * 4);   // pass-2 final f32 h
    float* hd1f  = (float*)alloc((size_t)HB * 4);
    float* hd2f  = (float*)alloc((size_t)HB * 4);
    unsigned* fl1 = (unsigned*)alloc(4096);         // 4 grp x 64 bn x 4 w
    unsigned* fl2 = (unsigned*)alloc(4096);

    cvt_x_kernel<<<(T_DIM * B_DIM * I_PAD) / 256, 256, 0, stream>>>(x, x_bf);
    auto cvt = [&](const float* in, bf16* out, int kin, int kp) {
        long total = 3072L * kp;
        cvt_pad<<<(int)((total + 255) / 256), 256, 0, stream>>>(in, out, kin, kp, total);
    };
    cvt(e_Wih0, wih0e, 118, 128);
    cvt(e_Whh0, whh0e, 1024, 1024);
    cvt(e_Wih1, wih1e, 1024, 1024);
    cvt(e_Whh1, whh1e, 1024, 1024);
    cvt(d_Wih0, wih0d, 118, 128);
    cvt(d_Whh0, whh0d, 1024, 1024);
    cvt(d_Wih1, wih1d, 1024, 1024);
    cvt(d_Whh1, whh1d, 1024, 1024);

    // deterministic per-launch state
    hipMemsetAsync(h1all, 0, (size_t)HB * 2, stream);   // h1 slot 0 = zeros
    hipMemsetAsync(h2pp,  0, 2ull * HB * 2, stream);    // h2 ping-pong = zeros
    hipMemsetAsync(fl1,   0, 4096, stream);
    hipMemsetAsync(fl2,   0, 4096, stream);

    // encoder layer 1 (SEQ): read slot t, write slot t+1
    gru_pass<128, true><<<256, 256, 0, stream>>>(
        x_bf, (long)B_DIM * I_PAD, wih0e, whh0e, e_bih0, e_bhh0,
        h1all, h1all + HB, nullptr, hf1f, T_DIM, fl1);

    // encoder layer 2 (!SEQ ping-pong): x input = h1(t) = slot t+1
    gru_pass<1024, false><<<256, 256, 0, stream>>>(
        h1all + HB, (long)HB, wih1e, whh1e, e_bih1, e_bhh1,
        h2pp, nullptr, nullptr, hf2f, T_DIM, fl2);
    // final h2(511) lands in ping-pong slot ((511+1)&1) = 0, f32 in hf2f

    // decoder cell 1: x = x[:,511,:], h = h1(511) (slot 512 / hf1f)
    gru_pass<128, true><<<256, 256, 0, stream>>>(
        x_bf + 511L * B_DIM * I_PAD, 0, wih0d, whh0d, d_bih0, d_bhh0,
        h1all + 512L * HB, hd1b, hf1f, hd1f, 1, nullptr);

    // decoder cell 2: x = hd1, h = h2 final (h2pp slot 0 / hf2f)
    gru_pass<1024, true><<<256, 256, 0, stream>>>(
        hd1b, 0, wih1d, whh1d, d_bih1, d_bhh1,
        h2pp, hd2b, hf2f, hd2f, 1, nullptr);

    head_kernel<<<1, 1024, 0, stream>>>(hd2f, fc_W, fc_b, out_W, out_b,
                                        (float*)d_out);
}